// Round 16
// baseline (199.672 us; speedup 1.0000x reference)
//
#include <hip/hip_runtime.h>
#include <hip/hip_bf16.h>
#include <math.h>

#define BB 16
#define CC 512
#define DD 64
#define NN 4096
#define EPSV 1e-6f

typedef __attribute__((ext_vector_type(8))) short short8;
typedef __attribute__((ext_vector_type(4))) short s16x4;
typedef __attribute__((ext_vector_type(4))) float f32x4;

__device__ __forceinline__ float softplus_f(float v) {
    return fmaxf(v, 0.0f) + log1pf(expf(-fabsf(v)));
}
__device__ __forceinline__ short bf16s(float f) {
    __hip_bfloat16 h = __float2bfloat16(f);
    return __builtin_bit_cast(short, h);
}
__device__ __forceinline__ float sbf16(short s) {
    return __bfloat162float(__builtin_bit_cast(__hip_bfloat16, s));
}

// ---- prep: Wcat bf16 [128][512] (blocks 0-255), zero KX (256-767), zero Ksum (768) ----
__global__ __launch_bounds__(256) void k_prep(const float* __restrict__ Wq,
                                              const float* __restrict__ Wk,
                                              __hip_bfloat16* __restrict__ Wcat,
                                              float* __restrict__ KX,
                                              float* __restrict__ Ksum) {
    int blk = blockIdx.x;
    if (blk < 256) {
        int i = blk * 256 + threadIdx.x;
        int j = i >> 9, c = i & 511;
        float v = (j < DD) ? Wq[j * CC + c] : Wk[(j - DD) * CC + c];
        Wcat[i] = __float2bfloat16(v);
    } else if (blk < 768) {
        int i = (blk - 256) * 256 + threadIdx.x;   // 512*256 f32x4 = 2MB
        f32x4 z = {0.f, 0.f, 0.f, 0.f};
        reinterpret_cast<f32x4*>(KX)[i] = z;
    } else {
        f32x4 z = {0.f, 0.f, 0.f, 0.f};
        reinterpret_cast<f32x4*>(Ksum)[threadIdx.x] = z;  // 1024 floats
    }
}

// ---- Q/K projection via MFMA, x staged through LDS, double-buffered.
//      BK=64: 8 chunk-iterations (was 16) to test/exploit fixed per-iteration cost.
//      ws unpadded with XOR chunk swizzle (slot = ch ^ (row&7), r13-verified).
//      Relaxed barrier (lgkmcnt only). Fused Ksum.
//      Qb[b][n][d] bf16 ; Kb[b][m][n] bf16 ----
__global__ __launch_bounds__(256) void k_proj(const float* __restrict__ x,
                                              const __hip_bfloat16* __restrict__ Wcat,
                                              const float* __restrict__ bq,
                                              const float* __restrict__ bk,
                                              __hip_bfloat16* __restrict__ Qb,
                                              __hip_bfloat16* __restrict__ Kb,
                                              float* __restrict__ Ksum) {
    __shared__ unsigned short xs[2][64][128];   // [c_local][n_local], unpadded (32KB)
    __shared__ unsigned short ws[2][128][64];   // [j][c_local], 16B-chunk swizzled (32KB)

    int b = blockIdx.y;
    int n_blk = blockIdx.x * 128;
    int t = threadIdx.x;
    int wave = t >> 6, lane = t & 63;
    int nwl = wave * 32;                    // wave's local n base
    int n_wave = n_blk + nwl;
    int l16 = lane & 15, g = lane >> 4;

    // staging assignments
    int sv = t & 31;                        // x: 4-float group along n
    int sc = t >> 5;                        // x: base c-row (0..7), rows sc+8i, i<8
    int wj = t >> 1;                        // W: row j (0..127)
    int wh = t & 1;                         // W: 32-elem half of the 64-c chunk

    const float* xb = x + (size_t)b * CC * NN + n_blk + sv * 4;
    const short8* wg = reinterpret_cast<const short8*>(Wcat) + (size_t)wj * 64;  // 64 chunks/row

    float xr[8][4];
    short8 wr[4];

    auto loadx = [&](int c0) {
#pragma unroll
        for (int i = 0; i < 8; ++i) {
            f32x4 v = *reinterpret_cast<const f32x4*>(xb + (size_t)(c0 + sc + i * 8) * NN);
            xr[i][0] = v[0]; xr[i][1] = v[1]; xr[i][2] = v[2]; xr[i][3] = v[3];
        }
    };
    auto loadw = [&](int ck) {              // ck in chunk-of-64 units; 16B chunks: ck*4 ..
#pragma unroll
        for (int k = 0; k < 4; ++k)
            wr[k] = wg[ck * 4 + wh * 2 + (k & 1) + (k >> 1) * ((size_t)0)];  // placeholder
    };
    (void)loadw;
    // W: per thread 4 chunks of 16B: global chunks ck*4 + wh*2 + k (k 0..1)? ->
    // simpler: per thread 4 consecutive chunks starting at wh*... use explicit below.

    auto loadw2 = [&](int ck) {
#pragma unroll
        for (int k = 0; k < 4; ++k)
            wr[k] = wg[(size_t)ck * 4 + wh * 4 + k - wh * 4 + (wh ? 4 : 0) * 0 + k * 0 + (wh * 4 + k)];
    };
    (void)loadw2;

    auto loadW = [&](int ck) {              // chunk base within row = ck*4? No: 64c = 4 chunks? 
        // 64 c = 64 shorts? NO: 64 c bf16 = 64 shorts = 128 B = 8 chunks of 16B.
        // per row per stage: 8 chunks; 2 threads/row -> 4 chunks each: slots wh*4+k
#pragma unroll
        for (int k = 0; k < 4; ++k)
            wr[k] = wg[(size_t)ck * 8 + wh * 4 + k];
    };
    auto writex = [&](int bi) {
#pragma unroll
        for (int i = 0; i < 8; ++i) {
            s16x4 pv;
#pragma unroll
            for (int j = 0; j < 4; ++j) pv[j] = bf16s(xr[i][j]);
            *reinterpret_cast<s16x4*>(&xs[bi][sc + i * 8][sv * 4]) = pv;
        }
    };
    auto writeW = [&](int bi) {
        short8* row8 = reinterpret_cast<short8*>(&ws[bi][wj][0]);   // 8 chunks/row
        int sw = wj & 7;
#pragma unroll
        for (int k = 0; k < 4; ++k) {
            int ch = wh * 4 + k;
            row8[ch ^ sw] = wr[k];
        }
    };

    f32x4 accQ[2][4] = {};                  // Q: D[n][j]
    f32x4 accK[4][2] = {};                  // K: D[j][n]

    loadx(0); loadW(0);
    writex(0); writeW(0);

    for (int ck = 0; ck < 8; ++ck) {        // 8 chunks of 64 c
        int cur = ck & 1;
        if (ck < 7) { loadx((ck + 1) * 64); loadW(ck + 1); }  // prefetch, stays in flight
        asm volatile("s_waitcnt lgkmcnt(0)" ::: "memory");
        __builtin_amdgcn_s_barrier();
#pragma unroll
        for (int sub = 0; sub < 2; ++sub) {  // two 32-c MFMA groups per chunk
            short8 xf[2], wf[8];
#pragma unroll
            for (int nf = 0; nf < 2; ++nf) {
                short8 v;
#pragma unroll
                for (int e = 0; e < 8; ++e)
                    v[e] = (short)xs[cur][sub * 32 + g * 8 + e][nwl + nf * 16 + l16];
                xf[nf] = v;
            }
#pragma unroll
            for (int jf = 0; jf < 8; ++jf) {
                int row = jf * 16 + l16;
                int slot = (sub * 4 + g) ^ (row & 7);
                wf[jf] = *reinterpret_cast<const short8*>(&ws[cur][row][slot * 8]);
            }
#pragma unroll
            for (int nf = 0; nf < 2; ++nf)
#pragma unroll
                for (int jf = 0; jf < 4; ++jf)
                    accQ[nf][jf] = __builtin_amdgcn_mfma_f32_16x16x32_bf16(xf[nf], wf[jf], accQ[nf][jf], 0, 0, 0);
#pragma unroll
            for (int jf = 0; jf < 4; ++jf)
#pragma unroll
                for (int nf = 0; nf < 2; ++nf)
                    accK[jf][nf] = __builtin_amdgcn_mfma_f32_16x16x32_bf16(wf[4 + jf], xf[nf], accK[jf][nf], 0, 0, 0);
        }
        if (ck < 7) { writex(cur ^ 1); writeW(cur ^ 1); }   // vmcnt waited here, after MFMAs
    }

    // Q epilogue: row n = n_wave + nf*16 + 4g + r, col j = jf*16 + l16
#pragma unroll
    for (int nf = 0; nf < 2; ++nf)
#pragma unroll
        for (int jf = 0; jf < 4; ++jf)
#pragma unroll
            for (int r = 0; r < 4; ++r) {
                int n = n_wave + nf * 16 + 4 * g + r;
                int j = jf * 16 + l16;
                float v = softplus_f(accQ[nf][jf][r] + bq[j]);
                Qb[((size_t)b * NN + n) * DD + j] = __float2bfloat16(v);
            }
    // K epilogue: row m = jf*16 + 4g + r, col n = n_wave + nf*16 + l16; fused Ksum
#pragma unroll
    for (int jf = 0; jf < 4; ++jf)
#pragma unroll
        for (int r = 0; r < 4; ++r) {
            int m = jf * 16 + 4 * g + r;
            float s = 0.f;
#pragma unroll
            for (int nf = 0; nf < 2; ++nf) {
                int n = n_wave + nf * 16 + l16;
                float v = softplus_f(accK[jf][nf][r] + bk[m]);
                Kb[((size_t)b * DD + m) * NN + n] = __float2bfloat16(v);
                s += v;
            }
            s += __shfl_xor(s, 1, 64);
            s += __shfl_xor(s, 2, 64);
            s += __shfl_xor(s, 4, 64);
            s += __shfl_xor(s, 8, 64);
            if (l16 == 0) atomicAdd(&Ksum[b * DD + m], s);
        }
}

// ---- KX[b][m][c] += sum_nn Kb[m][nn]*x[c][nn]  (MFMA, no LDS, split-K atomics)
//      r6 grid (2,16,BB): measured-best ----
__global__ __launch_bounds__(256) void k_kx(const __hip_bfloat16* __restrict__ Kb,
                                            const float* __restrict__ x,
                                            float* __restrict__ KX) {
    int b = blockIdx.z;
    int n0 = blockIdx.y * 256;                // 16 n-chunks
    int c0 = blockIdx.x * 256;                // 2 c-halves
    int wave = threadIdx.x >> 6, lane = threadIdx.x & 63;
    int cw = c0 + wave * 64;                  // wave owns 64 c-cols
    int l16 = lane & 15, g = lane >> 4;

    f32x4 acc[4][4] = {};                     // [mi][cj]
    const __hip_bfloat16* kp = Kb + (size_t)b * DD * NN;
    const float* xp = x + (size_t)b * CC * NN;

#pragma unroll
    for (int ks = 0; ks < 8; ++ks) {          // 256 n in steps of 32
        int nk = n0 + ks * 32 + g * 8;
        short8 af[4];
#pragma unroll
        for (int mi = 0; mi < 4; ++mi)
            af[mi] = *reinterpret_cast<const short8*>(kp + (size_t)(mi * 16 + l16) * NN + nk);
        short8 bf[4];
#pragma unroll
        for (int cj = 0; cj < 4; ++cj) {
            const float* xr = xp + (size_t)(cw + cj * 16 + l16) * NN + nk;
            f32x4 lo = *reinterpret_cast<const f32x4*>(xr);
            f32x4 hi = *reinterpret_cast<const f32x4*>(xr + 4);
            short8 v;
#pragma unroll
            for (int e = 0; e < 4; ++e) { v[e] = bf16s(lo[e]); v[4 + e] = bf16s(hi[e]); }
            bf[cj] = v;
        }
#pragma unroll
        for (int mi = 0; mi < 4; ++mi)
#pragma unroll
            for (int cj = 0; cj < 4; ++cj)
                acc[mi][cj] = __builtin_amdgcn_mfma_f32_16x16x32_bf16(af[mi], bf[cj], acc[mi][cj], 0, 0, 0);
    }
#pragma unroll
    for (int mi = 0; mi < 4; ++mi)
#pragma unroll
        for (int cj = 0; cj < 4; ++cj)
#pragma unroll
            for (int r = 0; r < 4; ++r) {
                int m = mi * 16 + 4 * g + r;
                int c = cw + cj * 16 + l16;
                atomicAdd(&KX[((size_t)(b * DD + m)) * CC + c], acc[mi][cj][r]);
            }
}

// ---- KVTb[b][c][m] = sum_cp KX[b][m][cp]*Wv[c][cp] + bv[c]*Ksum[b][m]
//      MFMA, no LDS, split hi/lo bf16 for ~fp32 accuracy. r6 grid: measured-best ----
__global__ __launch_bounds__(256) void k_kv(const float* __restrict__ KX,
                                            const float* __restrict__ Wv,
                                            const float* __restrict__ bv,
                                            const float* __restrict__ Ksum,
                                            __hip_bfloat16* __restrict__ KVTb) {
    int b = blockIdx.y;
    int c0 = blockIdx.x * 64;
    int wave = threadIdx.x >> 6, lane = threadIdx.x & 63;
    int cw = c0 + wave * 16;                  // wave owns 16 c-rows, all 64 m
    int l16 = lane & 15, g = lane >> 4;

    f32x4 acc[4] = {};                        // [mj]
    const float* wvp = Wv + (size_t)(cw + l16) * CC;
    const float* kxp = KX + (size_t)b * DD * CC;

#pragma unroll
    for (int ck = 0; ck < 16; ++ck) {         // 512 cp in steps of 32
        int cp = ck * 32 + g * 8;
        f32x4 w0 = *reinterpret_cast<const f32x4*>(wvp + cp);
        f32x4 w1 = *reinterpret_cast<const f32x4*>(wvp + cp + 4);
        short8 a_hi, a_lo;
#pragma unroll
        for (int e = 0; e < 4; ++e) {
            a_hi[e] = bf16s(w0[e]);     a_lo[e] = bf16s(w0[e] - sbf16(a_hi[e]));
            a_hi[4 + e] = bf16s(w1[e]); a_lo[4 + e] = bf16s(w1[e] - sbf16(a_hi[4 + e]));
        }
#pragma unroll
        for (int mj = 0; mj < 4; ++mj) {
            const float* kr = kxp + (size_t)(mj * 16 + l16) * CC + cp;
            f32x4 k0 = *reinterpret_cast<const f32x4*>(kr);
            f32x4 k1 = *reinterpret_cast<const f32x4*>(kr + 4);
            short8 b_hi, b_lo;
#pragma unroll
            for (int e = 0; e < 4; ++e) {
                b_hi[e] = bf16s(k0[e]);     b_lo[e] = bf16s(k0[e] - sbf16(b_hi[e]));
                b_hi[4 + e] = bf16s(k1[e]); b_lo[4 + e] = bf16s(k1[e] - sbf16(b_hi[4 + e]));
            }
            acc[mj] = __builtin_amdgcn_mfma_f32_16x16x32_bf16(a_hi, b_hi, acc[mj], 0, 0, 0);
            acc[mj] = __builtin_amdgcn_mfma_f32_16x16x32_bf16(a_lo, b_hi, acc[mj], 0, 0, 0);
            acc[mj] = __builtin_amdgcn_mfma_f32_16x16x32_bf16(a_hi, b_lo, acc[mj], 0, 0, 0);
        }
    }
#pragma unroll
    for (int mj = 0; mj < 4; ++mj)
#pragma unroll
        for (int r = 0; r < 4; ++r) {
            int c = cw + 4 * g + r;
            int m = mj * 16 + l16;
            KVTb[((size_t)b * CC + c) * DD + m] =
                __float2bfloat16(acc[mj][r] + bv[c] * Ksum[b * DD + m]);
        }
}

// ---- out[c][n] = x + (gamma/dot(Q[n],Ksum+eps)) * sum_m KVT[c][m]*Q[n][m]
//      MFMA K=64, norm fused in-register ----
__global__ __launch_bounds__(256) void k_out(const float* __restrict__ x,
                                             const __hip_bfloat16* __restrict__ Qb,
                                             const __hip_bfloat16* __restrict__ KVTb,
                                             const float* __restrict__ Ksum,
                                             const float* __restrict__ gamma,
                                             float* __restrict__ out) {
    int b = blockIdx.z;
    int c_blk = blockIdx.x * 128, n_blk = blockIdx.y * 128;
    int wave = threadIdx.x >> 6, lane = threadIdx.x & 63;
    int cw = c_blk + (wave >> 1) * 64, nw = n_blk + (wave & 1) * 64;
    int l16 = lane & 15, g = lane >> 4;

    float ksv[2][8];
#pragma unroll
    for (int ck = 0; ck < 2; ++ck)
#pragma unroll
        for (int e = 0; e < 8; ++e)
            ksv[ck][e] = Ksum[b * DD + (ck * 4 + g) * 8 + e] + EPSV;

    f32x4 acc[4][4] = {};
    float dot[4] = {0.f, 0.f, 0.f, 0.f};
    const short8* ap = reinterpret_cast<const short8*>(KVTb) + ((size_t)b * CC + cw) * 8;
    const short8* bp = reinterpret_cast<const short8*>(Qb) + ((size_t)b * NN + nw) * 8;
#pragma unroll
    for (int ck = 0; ck < 2; ++ck) {
        int ch = ck * 4 + g;
        short8 af[4], bf[4];
#pragma unroll
        for (int i = 0; i < 4; ++i) af[i] = ap[(size_t)(i * 16 + l16) * 8 + ch];
#pragma unroll
        for (int i = 0; i < 4; ++i) bf[i] = bp[(size_t)(i * 16 + l16) * 8 + ch];
#pragma unroll
        for (int j = 0; j < 4; ++j)
#pragma unroll
            for (int e = 0; e < 8; ++e)
                dot[j] = fmaf(sbf16(bf[j][e]), ksv[ck][e], dot[j]);
#pragma unroll
        for (int i = 0; i < 4; ++i)
#pragma unroll
            for (int j = 0; j < 4; ++j)
                acc[i][j] = __builtin_amdgcn_mfma_f32_16x16x32_bf16(af[i], bf[j], acc[i][j], 0, 0, 0);
    }
    float gm = gamma[0];
    float sc[4];
#pragma unroll
    for (int j = 0; j < 4; ++j) {
        float d = dot[j];
        d += __shfl_xor(d, 16, 64);
        d += __shfl_xor(d, 32, 64);
        sc[j] = gm / d;
    }
    const float* xb = x + (size_t)b * CC * NN;
    float* ob = out + (size_t)b * CC * NN;
#pragma unroll
    for (int i = 0; i < 4; ++i)
#pragma unroll
        for (int r = 0; r < 4; ++r) {
            int c = cw + i * 16 + 4 * g + r;
            size_t rowoff = (size_t)c * NN;
#pragma unroll
            for (int j = 0; j < 4; ++j) {
                int n = nw + j * 16 + l16;
                ob[rowoff + n] = xb[rowoff + n] + sc[j] * acc[i][j][r];
            }
        }
}

extern "C" void kernel_launch(void* const* d_in, const int* in_sizes, int n_in,
                              void* d_out, int out_size, void* d_ws, size_t ws_size,
                              hipStream_t stream) {
    const float* x     = (const float*)d_in[0];
    const float* Wq    = (const float*)d_in[1];
    const float* bq    = (const float*)d_in[2];
    const float* Wk    = (const float*)d_in[3];
    const float* bk    = (const float*)d_in[4];
    const float* Wv    = (const float*)d_in[5];
    const float* bv    = (const float*)d_in[6];
    const float* gamma = (const float*)d_in[7];
    float* out = (float*)d_out;

    float* ws    = (float*)d_ws;
    float* KX    = ws;                                   // B*D*C fp32 (2MB)
    float* Ksum  = KX + (size_t)BB * DD * CC;            // B*D fp32
    __hip_bfloat16* Qb   = (__hip_bfloat16*)(Ksum + BB * DD);  // B*N*D bf16
    __hip_bfloat16* Kb   = Qb + (size_t)BB * NN * DD;    // B*D*N bf16
    __hip_bfloat16* KVTb = Kb + (size_t)BB * DD * NN;    // B*C*D bf16
    __hip_bfloat16* Wcat = KVTb + (size_t)BB * CC * DD;  // 128*C bf16

    k_prep<<<dim3(769), dim3(256), 0, stream>>>(Wq, Wk, Wcat, KX, Ksum);
    k_proj<<<dim3(NN / 128, BB), dim3(256), 0, stream>>>(x, Wcat, bq, bk, Qb, Kb, Ksum);
    k_kx<<<dim3(2, 16, BB), dim3(256), 0, stream>>>(Kb, x, KX);
    k_kv<<<dim3(CC / 64, BB), dim3(256), 0, stream>>>(KX, Wv, bv, Ksum, KVTb);
    k_out<<<dim3(CC / 128, NN / 128, BB), dim3(256), 0, stream>>>(x, Qb, KVTb, Ksum, gamma, out);
}